// Round 3
// 77.326 us; speedup vs baseline: 1.0367x; 1.0367x over previous
//
#include <hip/hip_runtime.h>
#include <math.h>

// QNN: 8 qubits, DIM=256, 2 entangling layers, B samples.
//  - RX(x_q) fuses with layer-1 RX -> product state v_q (V0,V1).
//  - CNOT ring 1 folded into product expansion; rank-8 split (R7/R9):
//      S[row][col] = RF[row] * TH[(h1,h1^h0)][col0] * TC[col][r0]
//  - Layer-2: phi = A*S*B^T. R17: re/im contraction folded into K=32:
//      Tr/Ti = mfma_f32_16x16x32_f16(Silv, ilv(Art,-Ait)/ilv(Ait,Art))
//      Pr/Pi = mfma_f32_16x16x32_f16(ilv(Brf,-Bif)/ilv(Bif,Brf), Tilv)
//    Silv is the raw cmulh outputs {a0..a3} (packed (re,im) pairs ==
//    interleaved-K layout k=(lane>>4)*8+j, same layout as the verified
//    sign-table epilogue). 4 MFMAs/sample (was 8 chained 16x16x16),
//    zero v_perm, single-level MFMA deps.
//  - CNOT ring 2 + <Z_w> + reduction folded into a constant sign matrix
//    applied as mfma 16x16x32 f16 chain (R6), phi^T bit mapping (R12).
//    R17: split into two 4-deep chains + f4 add (halves serial latency).
// R16: SINGLE-KERNEL fusion (R13 math): A/B gate frags computed per-lane
//    in-kernel; layer-1 K tables inlined (hw trig); sign table constexpr.
//    d_ws unused.
// R19: identical to R17 — third submit after repeated infra failures
//    (container acquire; no kernel-side evidence of fault).

typedef float f2 __attribute__((ext_vector_type(2)));
typedef float f4 __attribute__((ext_vector_type(4)));
typedef _Float16 half8 __attribute__((ext_vector_type(8)));

// f32 complex mul, 2 VOP3P ops (verified R3-R15)
__device__ __forceinline__ f2 cmul_pk(f2 a, f2 b) {
    f2 t, d;
    asm("v_pk_mul_f32 %0, %1, %2 op_sel:[0,0] op_sel_hi:[0,1]"
        : "=v"(t) : "v"(a), "v"(b));
    asm("v_pk_fma_f32 %0, %1, %2, %3 op_sel:[1,1,0] op_sel_hi:[1,0,1] neg_lo:[1,0,0] neg_hi:[0,0,0]"
        : "=v"(d) : "v"(a), "v"(b), "v"(t));
    return d;
}
// packed-f16 complex mul (verified R9-R15)
__device__ __forceinline__ unsigned cmulh(unsigned a, unsigned b) {
    unsigned t, d;
    asm("v_pk_mul_f16 %0, %1, %2 op_sel:[0,0] op_sel_hi:[0,1]"
        : "=v"(t) : "v"(a), "v"(b));
    asm("v_pk_fma_f16 %0, %1, %2, %3 op_sel:[1,1,0] op_sel_hi:[1,0,1] neg_lo:[1,0,0] neg_hi:[0,0,0]"
        : "=v"(d) : "v"(a), "v"(b), "v"(t));
    return d;
}
__device__ __forceinline__ unsigned pkh(f2 v) {
    auto pk = __builtin_amdgcn_cvt_pkrtz(v.x, v.y);
    unsigned u; __builtin_memcpy(&u, &pk, 4);
    return u;
}
__device__ __forceinline__ half8 h8(uint4 u) {
    half8 h; __builtin_memcpy(&h, &u, 16);
    return h;
}
__device__ __forceinline__ f4 mfma32(half8 a, half8 b, f4 c) {
    return __builtin_amdgcn_mfma_f32_16x16x32_f16(a, b, c, 0, 0, 0);
}

// SU(2) gate-entry select: G[r][c] from first row (g00,g01);
// G[1][0] = -conj(g01), G[1][1] = conj(g00)   (matches R12 setup table)
__device__ __forceinline__ f2 gsel(const float* g, int r, int c) {
    f2 e0 = c ? (f2){g[2],  g[3]} : (f2){ g[0], g[1]};
    f2 e1 = c ? (f2){g[0], -g[1]} : (f2){-g[2], g[3]};
    return r ? e1 : e0;
}

// ---- constexpr sign table (input-independent; R12 phi^T bit mapping) ----
struct SgTab { unsigned short v[4096]; };
constexpr int cpop(int x) { int c = 0; while (x) { c += x & 1; x >>= 1; } return c; }
constexpr SgTab make_sg() {
    SgTab t{};
    const int cls[8] = {2, 0, 0, 0, 0, 0, 1, 2};
    const int msk[8] = {55, 12, 14, 15, 47, 63, 63, 63};
    for (int e = 0; e < 512; ++e) {
        int tt = e >> 6, l = e & 63, n = l & 15, quad = l >> 4;
        for (int j = 0; j < 8; ++j) {
            int k = tt*32 + quad*8 + j;
            int Lp = k >> 2, c = k & 3;
            unsigned short hv = 0;                      // f16 0.0
            if (n < 8 && c == cls[n])
                hv = (cpop(msk[n] & Lp) & 1) ? 0xBC00 : 0x3C00;  // -1 : +1
            t.v[e*8 + j] = hv;
        }
    }
    return t;
}
__device__ constexpr SgTab SG = make_sg();

// per-wave LDS (5888 B -> 6144; block 24576 -> 6 blocks/CU), R13 layout:
//   TH 512 | TC 2176 (stride 136) | RF 1024 (stride 64) |
//   R 2176 (4 rows x 544)  [VT 2048 aliased into R, dead before R writes]
#define WAVE_LDS 6144

__global__ __launch_bounds__(256, 6) void qnn_main(
        const float* __restrict__ x, const float* __restrict__ w,
        float* __restrict__ out, int B)
{
    __shared__ __align__(16) char smem[4 * WAVE_LDS];
    const int lane = threadIdx.x & 63;
    const int wid  = threadIdx.x >> 6;
    const int L = lane;
    const int b0 = (blockIdx.x * 4 + wid) * 16;
    if (b0 >= B) return;

    char* wb  = smem + wid * WAVE_LDS;
    char* THb = wb;                     // 512
    char* TCb = wb + 512;               // 2176
    char* RFb = wb + 2688;              // 1024
    char* Rb  = wb + 3712;              // 2176 (VT alias first)
    f4*   VT  = (f4*)Rb;

    const float CREV = 0.07957747154594767f;   // 0.5/(2*pi)
    const int hq  = L >> 4;             // quad
    const int col = L & 15;

    // ---- one-time per-lane frag build (layer-2 gate tensor products) ----
    // lane (hq,col) holds X[col][k2], k2 = hq*4+j: gate-k bits q1,q0,j1,j0.
    // R17: build K=32-interleaved frags directly:
    //   ABr = ilv(Art,-Ait), ABi = ilv(Ait,Art)   (stage-1 B-operands)
    //   BPr = ilv(Brf,-Bif), BPi = ilv(Bif,Brf)   (stage-2 A-operands)
    half8 ABr, ABi, BPr, BPi;
    {
        const int mb0 = (col>>3)&1, mb1 = (col>>2)&1, mb2 = (col>>1)&1, mb3 = col&1;
        const int q1 = (hq>>1)&1, q0 = hq&1;
        float gv[4][4];
#pragma unroll
        for (int half = 0; half < 2; ++half) {
#pragma unroll
            for (int q = 0; q < 4; ++q) {
                const float* wq = w + (8 + half*4 + q)*3;
                float ra = wq[0]*CREV, rb = wq[1]*CREV, rg = wq[2]*CREV;
                float ca = __builtin_amdgcn_cosf(ra), sa = __builtin_amdgcn_sinf(ra);
                float cb = __builtin_amdgcn_cosf(rb), sb = __builtin_amdgcn_sinf(rb);
                float cg = __builtin_amdgcn_cosf(rg), sg = __builtin_amdgcn_sinf(rg);
                float A = cb*ca, Bv = sb*sa, Cc = sb*ca, D = cb*sa;
                gv[q][0] = cg*A + sg*Bv;        // g00r
                gv[q][1] = cg*Bv - sg*A;        // g00i
                gv[q][2] = -(cg*Cc + sg*D);     // g01r
                gv[q][3] = sg*Cc - cg*D;        // g01i
            }
            f2 P01 = cmul_pk(gsel(gv[0], mb0, q1), gsel(gv[1], mb1, q0));
            f2 Xj[4];
#pragma unroll
            for (int j = 0; j < 4; ++j)
                Xj[j] = cmul_pk(P01, cmul_pk(gsel(gv[2], mb2, j>>1),
                                             gsel(gv[3], mb3, j&1)));
            // interleaved pairs: even k_new = re-path, odd k_new = im-path
            uint4 ur = { pkh((f2){Xj[0].x, -Xj[0].y}),
                         pkh((f2){Xj[1].x, -Xj[1].y}),
                         pkh((f2){Xj[2].x, -Xj[2].y}),
                         pkh((f2){Xj[3].x, -Xj[3].y}) };
            uint4 ui = { pkh((f2){Xj[0].y,  Xj[0].x}),
                         pkh((f2){Xj[1].y,  Xj[1].x}),
                         pkh((f2){Xj[2].y,  Xj[2].x}),
                         pkh((f2){Xj[3].y,  Xj[3].x}) };
            if (half == 0) { ABr = h8(ur); ABi = h8(ui); }
            else           { BPr = h8(ur); BPi = h8(ui); }
        }
    }
    const half8* sgt = (const half8*)SG.v;

    // ---- phase A: build V for 16 samples x 8 qubits (2 builds/lane) ----
    // K tables inlined: V0 = (ca*cg*cb + sa*sg*sb, sa*cg*sb - ca*sg*cb)
    //                   V1 = (ca*cg*sb + sa*sg*cb, ca*sg*sb - sa*cg*cb)
    {
        int sI = L >> 2, qp = (L & 3) * 2;
        float2 xv = ((const float2*)x)[(size_t)(b0 + sI)*4 + (L & 3)];
#pragma unroll
        for (int u = 0; u < 2; ++u) {
            int q = qp + u;
            float w0 = w[q*3+0], w1 = w[q*3+1], w2 = w[q*3+2];
            float ang = (u ? xv.y : xv.x) + w0;
            float ra = ang * CREV, rb = w1 * CREV, rg = w2 * CREV;
            float ca = __builtin_amdgcn_cosf(ra), sa = __builtin_amdgcn_sinf(ra);
            float cb = __builtin_amdgcn_cosf(rb), sb = __builtin_amdgcn_sinf(rb);
            float cg = __builtin_amdgcn_cosf(rg), sg = __builtin_amdgcn_sinf(rg);
            f4 v;
            v.x = ca*(cg*cb) + sa*(sg*sb);
            v.y = sa*(cg*sb) - ca*(sg*cb);
            v.z = ca*(cg*sb) + sa*(sg*cb);
            v.w = ca*(sg*sb) - sa*(cg*cb);
            VT[sI*8 + q] = v;
        }
    }
    // same-wave LDS is in-order; all regions per-wave -> no barriers

    // ---- phase B: build TH/TC/RF tables in f16 (4 lanes per sample) ----
    {
        int sI = L >> 2, j = L & 3;
        const f4* Vs = VT + sI*8;
        f4 q0v = Vs[0], q1v = Vs[1], q2v = Vs[2], q3v = Vs[3];
        f4 q4v = Vs[4], q5v = Vs[5], q6v = Vs[6], q7v = Vs[7];
        f2 V0a = {q0v.x,q0v.y}, V0b = {q0v.z,q0v.w};
        f2 V1a = {q1v.x,q1v.y}, V1b = {q1v.z,q1v.w};
        f2 V2a = {q2v.x,q2v.y}, V2b = {q2v.z,q2v.w};
        f2 V3a = {q3v.x,q3v.y}, V3b = {q3v.z,q3v.w};
        f2 V4a = {q4v.x,q4v.y}, V4bv = {q4v.z,q4v.w};
        f2 V5a = {q5v.x,q5v.y}, V5b = {q5v.z,q5v.w};
        f2 V6a = {q6v.x,q6v.y}, V6b = {q6v.z,q6v.w};
        f2 V7a = {q7v.x,q7v.y}, V7b = {q7v.z,q7v.w};
        // TH slot j = (t1,t2) = (j>>1, j&1); entries col0 = 0,1  (f16)
        int t1 = j >> 1, t2 = j & 1;
        f2 th0 = cmul_pk(t1 ? V0b : V0a, t2 ? V1b : V1a);
        f2 th1 = cmul_pk(t1 ? V0a : V0b, t2 ? V1a : V1b);
        *(uint2*)(THb + sI*32 + j*8) = (uint2){pkh(th0), pkh(th1)};
        // TC cols 4j..4j+3 (f16): col3 = j>>1, col2 = j&1 (R9 layout)
        int col3 = j >> 1, col2 = j & 1;
        f2 v5s  = (col3 ^ col2) ? V5b : V5a;
        f2 p6_0 = cmul_pk(v5s, col2 ? V6b : V6a);     // col1 = 0
        f2 p6_1 = cmul_pk(v5s, col2 ? V6a : V6b);     // col1 = 1
        f2 V4lo = col3 ? V4bv : V4a;                  // V4[col3]     (r0=0)
        f2 V4hi = col3 ? V4a : V4bv;                  // V4[1^col3]   (r0=1)
#pragma unroll
        for (int c = 0; c < 4; ++c) {
            int c1 = c >> 1, c0 = c & 1;
            f2 cf = cmul_pk(c1 ? p6_1 : p6_0, (c1 ^ c0) ? V7b : V7a);
            f2 e0 = cmul_pk(cf, V4lo);
            f2 e1 = cmul_pk(cf, V4hi);
            *(uint2*)(TCb + sI*136 + (4*j + c)*8) = (uint2){pkh(e0), pkh(e1)};
        }
        // RF rows 4j..4j+3 (f16): RF[row] = V2[row2^row1]*V3[row1^row0]
        unsigned rr[4];
#pragma unroll
        for (int r = 0; r < 4; ++r) {
            int r1 = r >> 1, r0 = r & 1;
            f2 rf = cmul_pk(((j & 1) ^ r1) ? V2b : V2a, (r1 ^ r0) ? V3b : V3a);
            rr[r] = pkh(rf);
        }
        *(uint4*)(RFb + sI*64 + j*16) = (uint4){rr[0], rr[1], rr[2], rr[3]};
    }

    // ---- hoisted lane constants ----
    const int th_t1 = hq >> 1, th_t2 = (hq >> 1) ^ (hq & 1);
    char* THl = THb + ((th_t1*2 + th_t2)*2 + (col & 1))*4;
    char* TCl = TCb + col*8;
    char* RFl = RFb + hq*16;
    char* Rw  = Rb + L*8;
    char* Rr  = Rb + (col & 3)*544 + hq*16;
    const f4 zz = {0.f, 0.f, 0.f, 0.f};

    for (int h = 0; h < 4; ++h) {
#pragma unroll
        for (int s4 = 0; s4 < 4; ++s4) {
            const int s = h*4 + s4;
            // ---- front-end (R9 form): a_r = RF[4hq+r] * (TH*TC[col][r&1]) --
            unsigned u  = *(const unsigned*)(THl + s*32);
            uint2   tc  = *(const uint2*)(TCl + s*136);
            uint4   rf  = *(const uint4*)(RFl + s*64);
            unsigned g0 = cmulh(u, tc.x);
            unsigned g1 = cmulh(u, tc.y);
            unsigned a0 = cmulh(rf.x, g0);
            unsigned a1 = cmulh(rf.y, g1);
            unsigned a2 = cmulh(rf.z, g0);
            unsigned a3 = cmulh(rf.w, g1);
            // a_j = S[quad*4+j][col], packed (re,im) pairs == interleaved-K
            // A-operand layout k_new = hq*8 + j  (k_old = k_new/2, parity=im)
            half8 Sfrag = h8((uint4){a0, a1, a2, a3});
            // ---- stage-1: T = S^T * A^T, re/im folded into K=32 (2 mfma) --
            f4 Tr4 = mfma32(Sfrag, ABr, zz);
            f4 Ti4 = mfma32(Sfrag, ABi, zz);
            half8 Tf = h8((uint4){ pkh((f2){Tr4[0], Ti4[0]}),
                                   pkh((f2){Tr4[1], Ti4[1]}),
                                   pkh((f2){Tr4[2], Ti4[2]}),
                                   pkh((f2){Tr4[3], Ti4[3]}) });
            // ---- stage-2: phi^T = B * T, re/im folded into K=32 (2 mfma) --
            f4 Pr4 = mfma32(BPr, Tf, zz);
            f4 Pi4 = mfma32(BPi, Tf, zz);
            // ---- probs + in-lane 4-WHT (over wires 6,7) -> 3 classes ----
            float Q0 = Pr4[0]*Pr4[0] + Pi4[0]*Pi4[0];
            float Q1 = Pr4[1]*Pr4[1] + Pi4[1]*Pi4[1];
            float Q2 = Pr4[2]*Pr4[2] + Pi4[2]*Pi4[2];
            float Q3 = Pr4[3]*Pr4[3] + Pi4[3]*Pi4[3];
            float s01 = Q0 + Q1, s23 = Q2 + Q3;
            float S00 = s01 + s23;
            float S10 = s01 - s23;              // sign by w6
            float S11 = (Q0 - Q1) - (Q2 - Q3);  // sign by w6^w7
            uint2 wv = { pkh((f2){S00, S10}), pkh((f2){S11, 0.f}) };
            *(uint2*)(Rw + s4*544) = wv;
        }
        // ---- epilogue: out[s][w] = R x Sgn (2x4 chained f16 MFMAs) ----
        f4 acc0 = zz, acc1 = zz;
#pragma unroll
        for (int tt = 0; tt < 4; ++tt) {
            uint4 rv0 = *(uint4*)(Rr + tt*64);
            uint4 rv1 = *(uint4*)(Rr + (tt+4)*64);
            half8 af0, af1;
            __builtin_memcpy(&af0, &rv0, 16);
            __builtin_memcpy(&af1, &rv1, 16);
            acc0 = mfma32(af0, sgt[tt*64 + L], acc0);
            acc1 = mfma32(af1, sgt[(tt+4)*64 + L], acc1);
        }
        f4 acc = acc0 + acc1;
        if (hq == 0 && col < 8) {       // rows 0..3 = samples h*4..h*4+3
            size_t base = (size_t)(b0 + h*4) * 8 + col;
            out[base     ] = acc[0];
            out[base +  8] = acc[1];
            out[base + 16] = acc[2];
            out[base + 24] = acc[3];
        }
    }
}

extern "C" void kernel_launch(void* const* d_in, const int* in_sizes, int n_in,
                              void* d_out, int out_size, void* d_ws, size_t ws_size,
                              hipStream_t stream) {
    const float* x = (const float*)d_in[0];
    const float* w = (const float*)d_in[1];
    float* outp    = (float*)d_out;
    int B = in_sizes[0] / 8;

    int blocks = (B + 63) / 64;           // 4 waves/block, 16 samples/wave
    qnn_main<<<blocks, 256, 0, stream>>>(x, w, outp, B);
}

// Round 4
// 77.294 us; speedup vs baseline: 1.0371x; 1.0004x over previous
//
#include <hip/hip_runtime.h>
#include <math.h>

// QNN: 8 qubits, DIM=256, 2 entangling layers, B samples.
//  - RX(x_q) fuses with layer-1 RX -> product state v_q (V0,V1).
//  - CNOT ring 1 folded into product expansion; rank-8 split (R7/R9):
//      S[row][col] = RF[row] * TH[(h1,h1^h0)][col0] * TC[col][r0]
//  - Layer-2: phi = A*S*B^T. R17: re/im contraction folded into K=32:
//      Tr/Ti = mfma_f32_16x16x32_f16(Silv, ilv(Art,-Ait)/ilv(Ait,Art))
//      Pr/Pi = mfma_f32_16x16x32_f16(ilv(Brf,-Bif)/ilv(Bif,Brf), Tilv)
//    Silv is the raw cmulh outputs {a0..a3} (packed (re,im) pairs ==
//    interleaved-K layout k=(lane>>4)*8+j, same layout as the verified
//    sign-table epilogue). 4 MFMAs/sample, zero v_perm, single-level deps.
//  - CNOT ring 2 + <Z_w> + reduction folded into a constant sign matrix
//    applied as mfma 16x16x32 f16 chain (R6), phi^T bit mapping (R12).
//    R17: split into two 4-deep chains + f4 add (halves serial latency).
// R16: SINGLE-KERNEL fusion (R13 math): A/B gate frags computed per-lane
//    in-kernel; layer-1 K tables inlined (hw trig); sign table constexpr.
//    d_ws unused.
// R20: __launch_bounds__(256,6) -> (256,4). The ",6" capped VGPRs at
//    ~84/wave; the kernel naturally wants ~110-140 (4x half8 frags +
//    4-sample pipelined inner loop) -> suspected spills / de-pipelining.
//    LDS (24.6KB/block) never limited occupancy. 4 waves/SIMD remains
//    ample TLP. Discriminator: no delta => kernel is a <=5us tail under
//    the ~72us harness reset floor.

typedef float f2 __attribute__((ext_vector_type(2)));
typedef float f4 __attribute__((ext_vector_type(4)));
typedef _Float16 half8 __attribute__((ext_vector_type(8)));

// f32 complex mul, 2 VOP3P ops (verified R3-R15)
__device__ __forceinline__ f2 cmul_pk(f2 a, f2 b) {
    f2 t, d;
    asm("v_pk_mul_f32 %0, %1, %2 op_sel:[0,0] op_sel_hi:[0,1]"
        : "=v"(t) : "v"(a), "v"(b));
    asm("v_pk_fma_f32 %0, %1, %2, %3 op_sel:[1,1,0] op_sel_hi:[1,0,1] neg_lo:[1,0,0] neg_hi:[0,0,0]"
        : "=v"(d) : "v"(a), "v"(b), "v"(t));
    return d;
}
// packed-f16 complex mul (verified R9-R15)
__device__ __forceinline__ unsigned cmulh(unsigned a, unsigned b) {
    unsigned t, d;
    asm("v_pk_mul_f16 %0, %1, %2 op_sel:[0,0] op_sel_hi:[0,1]"
        : "=v"(t) : "v"(a), "v"(b));
    asm("v_pk_fma_f16 %0, %1, %2, %3 op_sel:[1,1,0] op_sel_hi:[1,0,1] neg_lo:[1,0,0] neg_hi:[0,0,0]"
        : "=v"(d) : "v"(a), "v"(b), "v"(t));
    return d;
}
__device__ __forceinline__ unsigned pkh(f2 v) {
    auto pk = __builtin_amdgcn_cvt_pkrtz(v.x, v.y);
    unsigned u; __builtin_memcpy(&u, &pk, 4);
    return u;
}
__device__ __forceinline__ half8 h8(uint4 u) {
    half8 h; __builtin_memcpy(&h, &u, 16);
    return h;
}
__device__ __forceinline__ f4 mfma32(half8 a, half8 b, f4 c) {
    return __builtin_amdgcn_mfma_f32_16x16x32_f16(a, b, c, 0, 0, 0);
}

// SU(2) gate-entry select: G[r][c] from first row (g00,g01);
// G[1][0] = -conj(g01), G[1][1] = conj(g00)   (matches R12 setup table)
__device__ __forceinline__ f2 gsel(const float* g, int r, int c) {
    f2 e0 = c ? (f2){g[2],  g[3]} : (f2){ g[0], g[1]};
    f2 e1 = c ? (f2){g[0], -g[1]} : (f2){-g[2], g[3]};
    return r ? e1 : e0;
}

// ---- constexpr sign table (input-independent; R12 phi^T bit mapping) ----
struct SgTab { unsigned short v[4096]; };
constexpr int cpop(int x) { int c = 0; while (x) { c += x & 1; x >>= 1; } return c; }
constexpr SgTab make_sg() {
    SgTab t{};
    const int cls[8] = {2, 0, 0, 0, 0, 0, 1, 2};
    const int msk[8] = {55, 12, 14, 15, 47, 63, 63, 63};
    for (int e = 0; e < 512; ++e) {
        int tt = e >> 6, l = e & 63, n = l & 15, quad = l >> 4;
        for (int j = 0; j < 8; ++j) {
            int k = tt*32 + quad*8 + j;
            int Lp = k >> 2, c = k & 3;
            unsigned short hv = 0;                      // f16 0.0
            if (n < 8 && c == cls[n])
                hv = (cpop(msk[n] & Lp) & 1) ? 0xBC00 : 0x3C00;  // -1 : +1
            t.v[e*8 + j] = hv;
        }
    }
    return t;
}
__device__ constexpr SgTab SG = make_sg();

// per-wave LDS (5888 B -> 6144; block 24576), R13 layout:
//   TH 512 | TC 2176 (stride 136) | RF 1024 (stride 64) |
//   R 2176 (4 rows x 544)  [VT 2048 aliased into R, dead before R writes]
#define WAVE_LDS 6144

__global__ __launch_bounds__(256, 4) void qnn_main(
        const float* __restrict__ x, const float* __restrict__ w,
        float* __restrict__ out, int B)
{
    __shared__ __align__(16) char smem[4 * WAVE_LDS];
    const int lane = threadIdx.x & 63;
    const int wid  = threadIdx.x >> 6;
    const int L = lane;
    const int b0 = (blockIdx.x * 4 + wid) * 16;
    if (b0 >= B) return;

    char* wb  = smem + wid * WAVE_LDS;
    char* THb = wb;                     // 512
    char* TCb = wb + 512;               // 2176
    char* RFb = wb + 2688;              // 1024
    char* Rb  = wb + 3712;              // 2176 (VT alias first)
    f4*   VT  = (f4*)Rb;

    const float CREV = 0.07957747154594767f;   // 0.5/(2*pi)
    const int hq  = L >> 4;             // quad
    const int col = L & 15;

    // ---- one-time per-lane frag build (layer-2 gate tensor products) ----
    // lane (hq,col) holds X[col][k2], k2 = hq*4+j: gate-k bits q1,q0,j1,j0.
    // R17: build K=32-interleaved frags directly:
    //   ABr = ilv(Art,-Ait), ABi = ilv(Ait,Art)   (stage-1 B-operands)
    //   BPr = ilv(Brf,-Bif), BPi = ilv(Bif,Brf)   (stage-2 A-operands)
    half8 ABr, ABi, BPr, BPi;
    {
        const int mb0 = (col>>3)&1, mb1 = (col>>2)&1, mb2 = (col>>1)&1, mb3 = col&1;
        const int q1 = (hq>>1)&1, q0 = hq&1;
        float gv[4][4];
#pragma unroll
        for (int half = 0; half < 2; ++half) {
#pragma unroll
            for (int q = 0; q < 4; ++q) {
                const float* wq = w + (8 + half*4 + q)*3;
                float ra = wq[0]*CREV, rb = wq[1]*CREV, rg = wq[2]*CREV;
                float ca = __builtin_amdgcn_cosf(ra), sa = __builtin_amdgcn_sinf(ra);
                float cb = __builtin_amdgcn_cosf(rb), sb = __builtin_amdgcn_sinf(rb);
                float cg = __builtin_amdgcn_cosf(rg), sg = __builtin_amdgcn_sinf(rg);
                float A = cb*ca, Bv = sb*sa, Cc = sb*ca, D = cb*sa;
                gv[q][0] = cg*A + sg*Bv;        // g00r
                gv[q][1] = cg*Bv - sg*A;        // g00i
                gv[q][2] = -(cg*Cc + sg*D);     // g01r
                gv[q][3] = sg*Cc - cg*D;        // g01i
            }
            f2 P01 = cmul_pk(gsel(gv[0], mb0, q1), gsel(gv[1], mb1, q0));
            f2 Xj[4];
#pragma unroll
            for (int j = 0; j < 4; ++j)
                Xj[j] = cmul_pk(P01, cmul_pk(gsel(gv[2], mb2, j>>1),
                                             gsel(gv[3], mb3, j&1)));
            // interleaved pairs: even k_new = re-path, odd k_new = im-path
            uint4 ur = { pkh((f2){Xj[0].x, -Xj[0].y}),
                         pkh((f2){Xj[1].x, -Xj[1].y}),
                         pkh((f2){Xj[2].x, -Xj[2].y}),
                         pkh((f2){Xj[3].x, -Xj[3].y}) };
            uint4 ui = { pkh((f2){Xj[0].y,  Xj[0].x}),
                         pkh((f2){Xj[1].y,  Xj[1].x}),
                         pkh((f2){Xj[2].y,  Xj[2].x}),
                         pkh((f2){Xj[3].y,  Xj[3].x}) };
            if (half == 0) { ABr = h8(ur); ABi = h8(ui); }
            else           { BPr = h8(ur); BPi = h8(ui); }
        }
    }
    const half8* sgt = (const half8*)SG.v;

    // ---- phase A: build V for 16 samples x 8 qubits (2 builds/lane) ----
    // K tables inlined: V0 = (ca*cg*cb + sa*sg*sb, sa*cg*sb - ca*sg*cb)
    //                   V1 = (ca*cg*sb + sa*sg*cb, ca*sg*sb - sa*cg*cb)
    {
        int sI = L >> 2, qp = (L & 3) * 2;
        float2 xv = ((const float2*)x)[(size_t)(b0 + sI)*4 + (L & 3)];
#pragma unroll
        for (int u = 0; u < 2; ++u) {
            int q = qp + u;
            float w0 = w[q*3+0], w1 = w[q*3+1], w2 = w[q*3+2];
            float ang = (u ? xv.y : xv.x) + w0;
            float ra = ang * CREV, rb = w1 * CREV, rg = w2 * CREV;
            float ca = __builtin_amdgcn_cosf(ra), sa = __builtin_amdgcn_sinf(ra);
            float cb = __builtin_amdgcn_cosf(rb), sb = __builtin_amdgcn_sinf(rb);
            float cg = __builtin_amdgcn_cosf(rg), sg = __builtin_amdgcn_sinf(rg);
            f4 v;
            v.x = ca*(cg*cb) + sa*(sg*sb);
            v.y = sa*(cg*sb) - ca*(sg*cb);
            v.z = ca*(cg*sb) + sa*(sg*cb);
            v.w = ca*(sg*sb) - sa*(cg*cb);
            VT[sI*8 + q] = v;
        }
    }
    // same-wave LDS is in-order; all regions per-wave -> no barriers

    // ---- phase B: build TH/TC/RF tables in f16 (4 lanes per sample) ----
    {
        int sI = L >> 2, j = L & 3;
        const f4* Vs = VT + sI*8;
        f4 q0v = Vs[0], q1v = Vs[1], q2v = Vs[2], q3v = Vs[3];
        f4 q4v = Vs[4], q5v = Vs[5], q6v = Vs[6], q7v = Vs[7];
        f2 V0a = {q0v.x,q0v.y}, V0b = {q0v.z,q0v.w};
        f2 V1a = {q1v.x,q1v.y}, V1b = {q1v.z,q1v.w};
        f2 V2a = {q2v.x,q2v.y}, V2b = {q2v.z,q2v.w};
        f2 V3a = {q3v.x,q3v.y}, V3b = {q3v.z,q3v.w};
        f2 V4a = {q4v.x,q4v.y}, V4bv = {q4v.z,q4v.w};
        f2 V5a = {q5v.x,q5v.y}, V5b = {q5v.z,q5v.w};
        f2 V6a = {q6v.x,q6v.y}, V6b = {q6v.z,q6v.w};
        f2 V7a = {q7v.x,q7v.y}, V7b = {q7v.z,q7v.w};
        // TH slot j = (t1,t2) = (j>>1, j&1); entries col0 = 0,1  (f16)
        int t1 = j >> 1, t2 = j & 1;
        f2 th0 = cmul_pk(t1 ? V0b : V0a, t2 ? V1b : V1a);
        f2 th1 = cmul_pk(t1 ? V0a : V0b, t2 ? V1a : V1b);
        *(uint2*)(THb + sI*32 + j*8) = (uint2){pkh(th0), pkh(th1)};
        // TC cols 4j..4j+3 (f16): col3 = j>>1, col2 = j&1 (R9 layout)
        int col3 = j >> 1, col2 = j & 1;
        f2 v5s  = (col3 ^ col2) ? V5b : V5a;
        f2 p6_0 = cmul_pk(v5s, col2 ? V6b : V6a);     // col1 = 0
        f2 p6_1 = cmul_pk(v5s, col2 ? V6a : V6b);     // col1 = 1
        f2 V4lo = col3 ? V4bv : V4a;                  // V4[col3]     (r0=0)
        f2 V4hi = col3 ? V4a : V4bv;                  // V4[1^col3]   (r0=1)
#pragma unroll
        for (int c = 0; c < 4; ++c) {
            int c1 = c >> 1, c0 = c & 1;
            f2 cf = cmul_pk(c1 ? p6_1 : p6_0, (c1 ^ c0) ? V7b : V7a);
            f2 e0 = cmul_pk(cf, V4lo);
            f2 e1 = cmul_pk(cf, V4hi);
            *(uint2*)(TCb + sI*136 + (4*j + c)*8) = (uint2){pkh(e0), pkh(e1)};
        }
        // RF rows 4j..4j+3 (f16): RF[row] = V2[row2^row1]*V3[row1^row0]
        unsigned rr[4];
#pragma unroll
        for (int r = 0; r < 4; ++r) {
            int r1 = r >> 1, r0 = r & 1;
            f2 rf = cmul_pk(((j & 1) ^ r1) ? V2b : V2a, (r1 ^ r0) ? V3b : V3a);
            rr[r] = pkh(rf);
        }
        *(uint4*)(RFb + sI*64 + j*16) = (uint4){rr[0], rr[1], rr[2], rr[3]};
    }

    // ---- hoisted lane constants ----
    const int th_t1 = hq >> 1, th_t2 = (hq >> 1) ^ (hq & 1);
    char* THl = THb + ((th_t1*2 + th_t2)*2 + (col & 1))*4;
    char* TCl = TCb + col*8;
    char* RFl = RFb + hq*16;
    char* Rw  = Rb + L*8;
    char* Rr  = Rb + (col & 3)*544 + hq*16;
    const f4 zz = {0.f, 0.f, 0.f, 0.f};

    for (int h = 0; h < 4; ++h) {
#pragma unroll
        for (int s4 = 0; s4 < 4; ++s4) {
            const int s = h*4 + s4;
            // ---- front-end (R9 form): a_r = RF[4hq+r] * (TH*TC[col][r&1]) --
            unsigned u  = *(const unsigned*)(THl + s*32);
            uint2   tc  = *(const uint2*)(TCl + s*136);
            uint4   rf  = *(const uint4*)(RFl + s*64);
            unsigned g0 = cmulh(u, tc.x);
            unsigned g1 = cmulh(u, tc.y);
            unsigned a0 = cmulh(rf.x, g0);
            unsigned a1 = cmulh(rf.y, g1);
            unsigned a2 = cmulh(rf.z, g0);
            unsigned a3 = cmulh(rf.w, g1);
            // a_j = S[quad*4+j][col], packed (re,im) pairs == interleaved-K
            // A-operand layout k_new = hq*8 + j  (k_old = k_new/2, parity=im)
            half8 Sfrag = h8((uint4){a0, a1, a2, a3});
            // ---- stage-1: T = S^T * A^T, re/im folded into K=32 (2 mfma) --
            f4 Tr4 = mfma32(Sfrag, ABr, zz);
            f4 Ti4 = mfma32(Sfrag, ABi, zz);
            half8 Tf = h8((uint4){ pkh((f2){Tr4[0], Ti4[0]}),
                                   pkh((f2){Tr4[1], Ti4[1]}),
                                   pkh((f2){Tr4[2], Ti4[2]}),
                                   pkh((f2){Tr4[3], Ti4[3]}) });
            // ---- stage-2: phi^T = B * T, re/im folded into K=32 (2 mfma) --
            f4 Pr4 = mfma32(BPr, Tf, zz);
            f4 Pi4 = mfma32(BPi, Tf, zz);
            // ---- probs + in-lane 4-WHT (over wires 6,7) -> 3 classes ----
            float Q0 = Pr4[0]*Pr4[0] + Pi4[0]*Pi4[0];
            float Q1 = Pr4[1]*Pr4[1] + Pi4[1]*Pi4[1];
            float Q2 = Pr4[2]*Pr4[2] + Pi4[2]*Pi4[2];
            float Q3 = Pr4[3]*Pr4[3] + Pi4[3]*Pi4[3];
            float s01 = Q0 + Q1, s23 = Q2 + Q3;
            float S00 = s01 + s23;
            float S10 = s01 - s23;              // sign by w6
            float S11 = (Q0 - Q1) - (Q2 - Q3);  // sign by w6^w7
            uint2 wv = { pkh((f2){S00, S10}), pkh((f2){S11, 0.f}) };
            *(uint2*)(Rw + s4*544) = wv;
        }
        // ---- epilogue: out[s][w] = R x Sgn (2x4 chained f16 MFMAs) ----
        f4 acc0 = zz, acc1 = zz;
#pragma unroll
        for (int tt = 0; tt < 4; ++tt) {
            uint4 rv0 = *(uint4*)(Rr + tt*64);
            uint4 rv1 = *(uint4*)(Rr + (tt+4)*64);
            half8 af0, af1;
            __builtin_memcpy(&af0, &rv0, 16);
            __builtin_memcpy(&af1, &rv1, 16);
            acc0 = mfma32(af0, sgt[tt*64 + L], acc0);
            acc1 = mfma32(af1, sgt[(tt+4)*64 + L], acc1);
        }
        f4 acc = acc0 + acc1;
        if (hq == 0 && col < 8) {       // rows 0..3 = samples h*4..h*4+3
            size_t base = (size_t)(b0 + h*4) * 8 + col;
            out[base     ] = acc[0];
            out[base +  8] = acc[1];
            out[base + 16] = acc[2];
            out[base + 24] = acc[3];
        }
    }
}

extern "C" void kernel_launch(void* const* d_in, const int* in_sizes, int n_in,
                              void* d_out, int out_size, void* d_ws, size_t ws_size,
                              hipStream_t stream) {
    const float* x = (const float*)d_in[0];
    const float* w = (const float*)d_in[1];
    float* outp    = (float*)d_out;
    int B = in_sizes[0] / 8;

    int blocks = (B + 63) / 64;           // 4 waves/block, 16 samples/wave
    qnn_main<<<blocks, 256, 0, stream>>>(x, w, outp, B);
}